// Round 7
// baseline (252.260 us; speedup 1.0000x reference)
//
#include <hip/hip_runtime.h>

typedef unsigned short ushort_t;
typedef float v4f __attribute__((ext_vector_type(4)));
typedef short v8s __attribute__((ext_vector_type(8)));
typedef unsigned short u16x8 __attribute__((ext_vector_type(8)));
typedef unsigned short u16x2 __attribute__((ext_vector_type(2)));

// Problem constants
#define NN    10000
#define EE    160000
#define FIN   512
#define NH    8
#define C1    30
#define HC1   240   // NH*C1
#define HC1P  256   // padded
#define C2    64
#define HC2   512   // NH*C2
#define NCLS  64
#define BPP   2500  // blocks per part in agg (NN/4)

// ---------------- CSR build ----------------

__global__ __launch_bounds__(256) void hist_kernel(const int* __restrict__ dst,
                                                   int* __restrict__ counts, int E) {
    int e = blockIdx.x * blockDim.x + threadIdx.x;
    if (e < E) atomicAdd(&counts[dst[e]], 1);
}

__global__ __launch_bounds__(1024) void scan_kernel(const int* __restrict__ counts,
                                                    int* __restrict__ row_start, int n) {
    __shared__ int sums[1024];
    int t = threadIdx.x;
    const int chunk = (n + 1023) / 1024;
    int beg = t * chunk;
    int end = min(beg + chunk, n);
    int s = 0;
    for (int i = beg; i < end; ++i) s += counts[i];
    sums[t] = s;
    __syncthreads();
    for (int off = 1; off < 1024; off <<= 1) {
        int v = (t >= off) ? sums[t - off] : 0;
        __syncthreads();
        sums[t] += v;
        __syncthreads();
    }
    int run = (t == 0) ? 0 : sums[t - 1];
    for (int i = beg; i < end; ++i) {
        row_start[i] = run;
        run += counts[i];
    }
    if (t == 1023) row_start[n] = sums[1023];
}

__global__ __launch_bounds__(256) void scatter_kernel(const int* __restrict__ src,
                                                      const int* __restrict__ dst,
                                                      const int* __restrict__ row_start,
                                                      int* __restrict__ cursor,
                                                      int* __restrict__ edge_src, int E) {
    int e = blockIdx.x * blockDim.x + threadIdx.x;
    if (e < E) {
        int d = dst[e];
        int pos = row_start[d] + atomicAdd(&cursor[d], 1);
        edge_src[pos] = src[e];
    }
}

// ---------------- bf16 helpers ----------------

__device__ __forceinline__ void split1(float v, ushort_t& h, ushort_t& l) {
    unsigned u = __float_as_uint(v);
    unsigned rh = u + 0x7FFFu + ((u >> 16) & 1u);
    h = (ushort_t)(rh >> 16);
    float hf = __uint_as_float((unsigned)h << 16);
    float rem = v - hf;
    unsigned u2 = __float_as_uint(rem);
    unsigned rl = u2 + 0x7FFFu + ((u2 >> 16) & 1u);
    l = (ushort_t)(rl >> 16);
}

__device__ __forceinline__ ushort_t f2bf(float v) {
    unsigned u = __float_as_uint(v);
    return (ushort_t)((u + 0x7FFFu + ((u >> 16) & 1u)) >> 16);
}

__device__ __forceinline__ float bf2f(ushort_t u) {
    return __uint_as_float((unsigned)u << 16);
}

// ---------------- merged weight transpose+split (one launch) ----------------

__device__ __forceinline__ void tsplit_one(const float* B, ushort_t* th, ushort_t* tl,
                                           int idx, int K, int N, int KP) {
    int n = idx / KP;
    int k = idx - n * KP;
    float v = (n < N && k < K) ? B[(size_t)k * N + n] : 0.f;
    ushort_t h, l;
    split1(v, h, l);
    th[idx] = h;
    tl[idx] = l;
}

#define TS1 (HC1P * FIN)
#define TS2 (HC2 * HC1P)
#define TS3 (NCLS * HC2)

__global__ __launch_bounds__(256) void transpose_split_all(
    const float* __restrict__ W1, const float* __restrict__ W2,
    const float* __restrict__ Wl,
    ushort_t* __restrict__ t1h, ushort_t* __restrict__ t1l,
    ushort_t* __restrict__ t2h, ushort_t* __restrict__ t2l,
    ushort_t* __restrict__ t3h, ushort_t* __restrict__ t3l) {
    int idx = blockIdx.x * 256 + threadIdx.x;
    if (idx < TS1) {
        tsplit_one(W1, t1h, t1l, idx, FIN, HC1, FIN);
    } else if (idx < TS1 + TS2) {
        tsplit_one(W2, t2h, t2l, idx - TS1, HC1, HC2, HC1P);
    } else if (idx < TS1 + TS2 + TS3) {
        tsplit_one(Wl, t3h, t3l, idx - TS1 - TS2, HC2, NCLS, HC2);
    }
}

// ---------------- split-bf16 MFMA GEMM ----------------
// C[M x NP] = A[M x K] @ B; B pre-transposed/split [NP][K] bf16 hi/lo.
// Tile (32*TM) x (32*TN), BK=32, 256 threads = 4 waves (2x2),
// each wave (16*TM) x (16*TN). K%32==0.
// ATT (TN==4): emit asrc/adst per (row, head) — BN=128 covers 2 heads of 64.

template <int TM, int TN, bool BIAS, bool WF32, bool WBF, bool ATT>
__global__ __launch_bounds__(256) void gemm_mfma(const float* __restrict__ A,
                                                 const ushort_t* __restrict__ Bth,
                                                 const ushort_t* __restrict__ Btl,
                                                 const float* __restrict__ bias,
                                                 float* __restrict__ C,
                                                 ushort_t* __restrict__ Cbf,
                                                 const float* __restrict__ att_s,
                                                 const float* __restrict__ att_d,
                                                 float* __restrict__ asrc,
                                                 float* __restrict__ adst,
                                                 int M, int K, int CS) {
    constexpr int ROWS = 32 * TM;
    constexpr int BN = 32 * TN;
    constexpr int SK = 40;  // LDS stride (shorts): 2-way conflicts max (free)
    __shared__ ushort_t Ah[ROWS * SK], Al[ROWS * SK];
    __shared__ ushort_t Bh[BN * SK], Bl[BN * SK];
    const int t    = threadIdx.x;
    const int lane = t & 63;
    const int wave = t >> 6;
    const int quad = lane >> 4;
    const int l16  = lane & 15;
    const int wm   = wave >> 1;
    const int wn   = wave & 1;
    const int bm   = blockIdx.x * ROWS;
    const int bn   = blockIdx.y * BN;

    v4f acc[TM][TN];
    #pragma unroll
    for (int i = 0; i < TM; ++i)
        #pragma unroll
        for (int j = 0; j < TN; ++j) acc[i][j] = 0.f;

    for (int k0 = 0; k0 < K; k0 += 32) {
        if (k0) __syncthreads();
        // stage A (fp32 -> hi/lo bf16): ROWS rows x 4 chunks
        #pragma unroll
        for (int idx = t; idx < ROWS * 4; idx += 256) {
            int row = idx >> 2;
            int kcb = (idx & 3) * 8;
            int gm = bm + row;
            float va[8];
            if (gm < M) {
                const float* Ap = A + (size_t)gm * K + k0 + kcb;
                float4 p = *(const float4*)Ap;
                float4 q = *(const float4*)(Ap + 4);
                va[0] = p.x; va[1] = p.y; va[2] = p.z; va[3] = p.w;
                va[4] = q.x; va[5] = q.y; va[6] = q.z; va[7] = q.w;
            } else {
                #pragma unroll
                for (int i = 0; i < 8; ++i) va[i] = 0.f;
            }
            u16x8 hv, lv;
            #pragma unroll
            for (int i = 0; i < 8; ++i) {
                ushort_t h, l;
                split1(va[i], h, l);
                hv[i] = h;
                lv[i] = l;
            }
            *(u16x8*)&Ah[row * SK + kcb] = hv;
            *(u16x8*)&Al[row * SK + kcb] = lv;
        }
        // stage B: BN rows x 4 chunks
        #pragma unroll
        for (int idx = t; idx < BN * 4; idx += 256) {
            int row = idx >> 2;
            int kcb = (idx & 3) * 8;
            size_t go = (size_t)(bn + row) * K + k0 + kcb;
            *(u16x8*)&Bh[row * SK + kcb] = *(const u16x8*)(Bth + go);
            *(u16x8*)&Bl[row * SK + kcb] = *(const u16x8*)(Btl + go);
        }
        __syncthreads();

        v8s ah[TM], al2[TM], bh2[TN], bl2[TN];
        #pragma unroll
        for (int tt = 0; tt < TM; ++tt) {
            int ma = (wm * 16 * TM + tt * 16 + l16) * SK + quad * 8;
            ah[tt]  = *(const v8s*)&Ah[ma];
            al2[tt] = *(const v8s*)&Al[ma];
        }
        #pragma unroll
        for (int tn = 0; tn < TN; ++tn) {
            int nb = (wn * 16 * TN + tn * 16 + l16) * SK + quad * 8;
            bh2[tn] = *(const v8s*)&Bh[nb];
            bl2[tn] = *(const v8s*)&Bl[nb];
        }
        #pragma unroll
        for (int tm = 0; tm < TM; ++tm)
            #pragma unroll
            for (int tn = 0; tn < TN; ++tn) {
                acc[tm][tn] = __builtin_amdgcn_mfma_f32_16x16x32_bf16(
                    ah[tm], bh2[tn], acc[tm][tn], 0, 0, 0);
                acc[tm][tn] = __builtin_amdgcn_mfma_f32_16x16x32_bf16(
                    ah[tm], bl2[tn], acc[tm][tn], 0, 0, 0);
                acc[tm][tn] = __builtin_amdgcn_mfma_f32_16x16x32_bf16(
                    al2[tm], bh2[tn], acc[tm][tn], 0, 0, 0);
            }
    }

    // epilogue: C/D layout col=lane&15, row=quad*4+reg
    #pragma unroll
    for (int tm = 0; tm < TM; ++tm) {
        #pragma unroll
        for (int tn = 0; tn < TN; ++tn) {
            int row0 = bm + wm * 16 * TM + tm * 16 + quad * 4;
            int col  = bn + wn * 16 * TN + tn * 16 + l16;
            float badd = BIAS ? bias[col] : 0.f;
            #pragma unroll
            for (int reg = 0; reg < 4; ++reg) {
                int row = row0 + reg;
                if (row < M) {
                    float v = acc[tm][tn][reg] + badd;
                    if (WF32) C[(size_t)row * CS + col] = v;
                    if (WBF) Cbf[(size_t)row * CS + col] = f2bf(v);
                }
            }
        }
    }

    // fused attention scores (layer-2 layout: head = col/64)
    if constexpr (ATT) {
        float aS[TN], aD[TN];
        #pragma unroll
        for (int tn = 0; tn < TN; ++tn) {
            int col = bn + wn * 16 * TN + tn * 16 + l16;
            aS[tn] = att_s[col];
            aD[tn] = att_d[col];
        }
        const int head = blockIdx.y * 2 + wn;  // BN=128 -> 2 heads/block
        #pragma unroll
        for (int tm = 0; tm < TM; ++tm) {
            #pragma unroll
            for (int reg = 0; reg < 4; ++reg) {
                float ss = 0.f, sd = 0.f;
                #pragma unroll
                for (int tn = 0; tn < TN; ++tn) {
                    ss += acc[tm][tn][reg] * aS[tn];
                    sd += acc[tm][tn][reg] * aD[tn];
                }
                #pragma unroll
                for (int off = 1; off < 16; off <<= 1) {
                    ss += __shfl_xor(ss, off);
                    sd += __shfl_xor(sd, off);
                }
                if (l16 == 0) {
                    int row = bm + wm * 16 * TM + tm * 16 + quad * 4 + reg;
                    if (row < M) {
                        asrc[row * NH + head] = ss;
                        adst[row * NH + head] = sd;
                    }
                }
            }
        }
    }
}

// ---------------- attention coefficients (layer 1 only) ----------------

template <int C, int S>
__global__ __launch_bounds__(256) void att_kernel(const float* __restrict__ hpre,
                                                  const float* __restrict__ a_src,
                                                  const float* __restrict__ a_dst,
                                                  float* __restrict__ asrc,
                                                  float* __restrict__ adst, int n) {
    int idx = blockIdx.x * blockDim.x + threadIdx.x;
    if (idx >= n * NH) return;
    int node = idx >> 3, h = idx & 7;
    const float* row = hpre + (size_t)node * S + h * C;
    float s1 = 0.f, s2 = 0.f;
    #pragma unroll 4
    for (int i = 0; i < C; ++i) {
        float v = row[i];
        s1 += v * a_src[h * C + i];
        s2 += v * a_dst[h * C + i];
    }
    asrc[idx] = s1;
    adst[idx] = s2;
}

// ---------------- column-sliced, phase-ordered softmax aggregation ----------------
// SPLIT column slices; grid is part-major (blocks [part*BPP, (part+1)*BPP)) so
// each phase's 2ch/lane slice (RSB/SPLIT chans = 2.56 MB) is XCD-L2-resident.
// 1 wave per (node, part); 2 channels per lane; head uniform per lane (c0 even).
// Software-pipelined edge loop (prefetch depth 1, unroll 4).

template <int RSB, int NCH, int C, int SPLIT, int RSO, bool ELU>
__global__ __launch_bounds__(256) void agg_sl(const ushort_t* __restrict__ hb,
                                              const float* __restrict__ asrc,
                                              const float* __restrict__ adst,
                                              const int* __restrict__ row_start,
                                              const int* __restrict__ edge_src,
                                              const float* __restrict__ bias,
                                              float* __restrict__ out) {
    constexpr int SLICE = RSB / SPLIT;
    const int part = blockIdx.x / BPP;
    const int d    = (blockIdx.x - part * BPP) * 4 + (threadIdx.x >> 6);
    const int lane = threadIdx.x & 63;

    const int c0   = SLICE * part + 2 * lane;
    const bool v0  = (c0 < NCH);
    const bool v1  = (c0 + 1 < NCH);
    const int h    = v0 ? (c0 / C) : 0;

    const float adh = (lane < NH) ? adst[d * NH + lane] : 0.f;

    float m, s;
    float ax, ay;
    {
        float a = (lane < NH) ? asrc[d * NH + lane] + adh : 0.f;
        a = fmaxf(a, 0.2f * a);
        m = a;
        s = 1.f;
        u16x2 r = *(const u16x2*)(hb + (size_t)d * RSB + c0);
        ax = bf2f(r[0]);
        ay = bf2f(r[1]);
    }

    const int beg = row_start[d];
    const int end = row_start[d + 1];

    auto LD = [&](int eb, u16x2* rr, float* ss) {
        int i0 = edge_src[eb], i1 = edge_src[eb + 1];
        int i2 = edge_src[eb + 2], i3 = edge_src[eb + 3];
        rr[0] = *(const u16x2*)(hb + (size_t)i0 * RSB + c0);
        rr[1] = *(const u16x2*)(hb + (size_t)i1 * RSB + c0);
        rr[2] = *(const u16x2*)(hb + (size_t)i2 * RSB + c0);
        rr[3] = *(const u16x2*)(hb + (size_t)i3 * RSB + c0);
        if (lane < NH) {
            ss[0] = asrc[i0 * NH + lane];
            ss[1] = asrc[i1 * NH + lane];
            ss[2] = asrc[i2 * NH + lane];
            ss[3] = asrc[i3 * NH + lane];
        } else {
            ss[0] = ss[1] = ss[2] = ss[3] = 0.f;
        }
    };
    auto PR = [&](const u16x2* rr, const float* ss) {
        float a0 = ss[0] + adh, a1 = ss[1] + adh, a2 = ss[2] + adh, a3 = ss[3] + adh;
        a0 = fmaxf(a0, 0.2f * a0);
        a1 = fmaxf(a1, 0.2f * a1);
        a2 = fmaxf(a2, 0.2f * a2);
        a3 = fmaxf(a3, 0.2f * a3);
        float mn = fmaxf(m, fmaxf(fmaxf(a0, a1), fmaxf(a2, a3)));
        float al = __expf(m - mn);
        float w0 = __expf(a0 - mn);
        float w1 = __expf(a1 - mn);
        float w2 = __expf(a2 - mn);
        float w3 = __expf(a3 - mn);
        s = s * al + (w0 + w1) + (w2 + w3);
        m = mn;
        float alc = __shfl(al, h);
        float c0w = __shfl(w0, h);
        float c1w = __shfl(w1, h);
        float c2w = __shfl(w2, h);
        float c3w = __shfl(w3, h);
        ax = ax * alc + c0w * bf2f(rr[0][0]) + c1w * bf2f(rr[1][0]) +
             c2w * bf2f(rr[2][0]) + c3w * bf2f(rr[3][0]);
        ay = ay * alc + c0w * bf2f(rr[0][1]) + c1w * bf2f(rr[1][1]) +
             c2w * bf2f(rr[2][1]) + c3w * bf2f(rr[3][1]);
    };

    int e = beg;
    const int ng = (end - beg) >> 2;
    if (ng > 0) {
        u16x2 cr[4];
        float cs[4];
        LD(e, cr, cs);
        for (int g = 1; g < ng; ++g) {
            u16x2 nr[4];
            float ns[4];
            LD(e + 4 * g, nr, ns);   // issue next group's loads
            PR(cr, cs);              // compute current while in flight
            #pragma unroll
            for (int j = 0; j < 4; ++j) { cr[j] = nr[j]; cs[j] = ns[j]; }
        }
        PR(cr, cs);
        e += 4 * ng;
    }
    for (; e < end; ++e) {
        int i0 = edge_src[e];
        u16x2 r0 = *(const u16x2*)(hb + (size_t)i0 * RSB + c0);
        float a0 = (lane < NH) ? asrc[i0 * NH + lane] + adh : 0.f;
        a0 = fmaxf(a0, 0.2f * a0);
        float mn = fmaxf(m, a0);
        float al = __expf(m - mn);
        float w0 = __expf(a0 - mn);
        s = s * al + w0;
        m = mn;
        float alc = __shfl(al, h);
        float c0w = __shfl(w0, h);
        ax = ax * alc + c0w * bf2f(r0[0]);
        ay = ay * alc + c0w * bf2f(r0[1]);
    }

    float inv = 1.f / s;
    float ivc = __shfl(inv, h);
    float bx = v0 ? bias[c0] : 0.f;
    float by = v1 ? bias[c0 + 1] : 0.f;
    float ox = v0 ? (ax * ivc + bx) : 0.f;   // pad channels -> exact zero
    float oy = v1 ? (ay * ivc + by) : 0.f;
    if (ELU) {
        ox = (ox > 0.f) ? ox : __expf(ox) - 1.f;
        oy = (oy > 0.f) ? oy : __expf(oy) - 1.f;
    }
    float2 o;
    o.x = ox;
    o.y = oy;
    *(float2*)(out + (size_t)d * RSO + c0) = o;
}

// ---------------- launch ----------------

extern "C" void kernel_launch(void* const* d_in, const int* in_sizes, int n_in,
                              void* d_out, int out_size, void* d_ws, size_t ws_size,
                              hipStream_t stream) {
    const float* x      = (const float*)d_in[0];
    const int*   eidx   = (const int*)d_in[1];   // [2, E]
    const float* W1     = (const float*)d_in[2];
    const float* a1_src = (const float*)d_in[3];
    const float* a1_dst = (const float*)d_in[4];
    const float* b1     = (const float*)d_in[5];
    const float* W2     = (const float*)d_in[6];
    const float* a2_src = (const float*)d_in[7];
    const float* a2_dst = (const float*)d_in[8];
    const float* b2     = (const float*)d_in[9];
    const float* Wlin   = (const float*)d_in[10];
    const float* blin   = (const float*)d_in[11];

    const int* src = eidx;        // row 0
    const int* dst = eidx + EE;   // row 1

    float* out0  = (float*)d_out;                      // [N, NCLS]
    float* h_out = (float*)d_out + (size_t)NN * NCLS;  // [N, HC2] (output 1)

    // workspace layout: floats, then ushorts, then ints
    float* f = (float*)d_ws;
    float* h1p   = f;                         // [NN][HC1P] fp32 (att1 input)
    float* h1    = h1p + (size_t)NN * HC1P;   // [NN][HC1P] fp32 (L2 GEMM A input)
    float* asrc1 = h1 + (size_t)NN * HC1P;
    float* adst1 = asrc1 + NN * NH;
    float* asrc2 = adst1 + NN * NH;
    float* adst2 = asrc2 + NN * NH;
    ushort_t* w1t_h = (ushort_t*)(adst2 + NN * NH);  // [HC1P][FIN]
    ushort_t* w1t_l = w1t_h + TS1;
    ushort_t* w2t_h = w1t_l + TS1;                   // [HC2][HC1P]
    ushort_t* w2t_l = w2t_h + TS2;
    ushort_t* wlt_h = w2t_l + TS2;                   // [NCLS][HC2]
    ushort_t* wlt_l = wlt_h + TS3;
    ushort_t* h1p_bf = wlt_l + TS3;                  // [NN][HC1P] bf16 shadow
    ushort_t* h2p_bf = h1p_bf + (size_t)NN * HC1P;   // [NN][HC2] bf16 shadow
    int* counts    = (int*)(h2p_bf + (size_t)NN * HC2);
    int* cursor    = counts + NN;
    int* row_start = cursor + NN;            // N+1
    int* edge_src  = row_start + NN + 1;     // E

    hipMemsetAsync(counts, 0, 2 * NN * sizeof(int), stream);

    // all weight transposes + hi/lo splits in one launch
    transpose_split_all<<<(TS1 + TS2 + TS3 + 255) / 256, 256, 0, stream>>>(
        W1, W2, Wlin, w1t_h, w1t_l, w2t_h, w2t_l, wlt_h, wlt_l);

    // CSR by dst
    hist_kernel<<<(EE + 255) / 256, 256, 0, stream>>>(dst, counts, EE);
    scan_kernel<<<1, 1024, 0, stream>>>(counts, row_start, NN);
    scatter_kernel<<<(EE + 255) / 256, 256, 0, stream>>>(src, dst, row_start, cursor,
                                                         edge_src, EE);

    const int MB = (NN + 63) / 64;  // 157

    // Layer 1: h1p[NN][256] = x @ W1 (fp32 + bf16 shadow), 64x128 tiles
    {
        dim3 grid(MB, HC1P / 128);
        gemm_mfma<2, 4, false, true, true, false><<<grid, 256, 0, stream>>>(
            x, w1t_h, w1t_l, nullptr, h1p, h1p_bf, nullptr, nullptr, nullptr, nullptr,
            NN, FIN, HC1P);
    }
    att_kernel<C1, HC1P><<<(NN * NH + 255) / 256, 256, 0, stream>>>(h1p, a1_src, a1_dst,
                                                                    asrc1, adst1, NN);
    // agg1: 2 column slices of 128 ch, phase-ordered
    agg_sl<HC1P, HC1, C1, 2, HC1P, true><<<BPP * 2, 256, 0, stream>>>(
        h1p_bf, asrc1, adst1, row_start, edge_src, b1, h1);

    // Layer 2: bf16 shadow only + fused att2 scores, 64x128 tiles (2 heads/block)
    {
        dim3 grid(MB, HC2 / 128);
        gemm_mfma<2, 4, false, false, true, true><<<grid, 256, 0, stream>>>(
            h1, w2t_h, w2t_l, nullptr, nullptr, h2p_bf, a2_src, a2_dst, asrc2, adst2,
            NN, HC1P, HC2);
    }
    // agg2: 4 column slices of 128 ch, phase-ordered
    agg_sl<HC2, HC2, C2, 4, HC2, false><<<BPP * 4, 256, 0, stream>>>(
        h2p_bf, asrc2, adst2, row_start, edge_src, b2, h_out);

    // Head: out0 = h_out @ Wlin + blin, 32x64 tiles (313 blocks)
    {
        dim3 grid((NN + 31) / 32, NCLS / 64);
        gemm_mfma<1, 2, true, true, false, false><<<grid, 256, 0, stream>>>(
            h_out, wlt_h, wlt_l, blin, out0, nullptr, nullptr, nullptr, nullptr, nullptr,
            NN, HC2, NCLS);
    }
}

// Round 8
// 232.192 us; speedup vs baseline: 1.0864x; 1.0864x over previous
//
#include <hip/hip_runtime.h>
#include <type_traits>

typedef unsigned short ushort_t;
typedef float v4f __attribute__((ext_vector_type(4)));
typedef short v8s __attribute__((ext_vector_type(8)));
typedef unsigned short u16x8 __attribute__((ext_vector_type(8)));
typedef unsigned short u16x4v __attribute__((ext_vector_type(4)));

// Problem constants
#define NN    10000
#define EE    160000
#define FIN   512
#define NH    8
#define C1    30
#define HC1   240   // NH*C1 (original layer-1 width)
#define HC1P  256   // padded: 8 heads x 32 (head h at cols [32h, 32h+30))
#define C2    64
#define HC2   512   // NH*C2
#define NCLS  64

#define TS1 (HC1P * FIN)   // w1t  [256][512]
#define TS2 (HC2 * HC1P)   // w2t  [512][256]
#define TS3 (NCLS * HC2)   // wlt  [64][512]

// ---------------- CSR scan / scatter ----------------

__global__ __launch_bounds__(1024) void scan_kernel(const int* __restrict__ counts,
                                                    int* __restrict__ row_start, int n) {
    __shared__ int sums[1024];
    int t = threadIdx.x;
    const int chunk = (n + 1023) / 1024;
    int beg = t * chunk;
    int end = min(beg + chunk, n);
    int s = 0;
    for (int i = beg; i < end; ++i) s += counts[i];
    sums[t] = s;
    __syncthreads();
    for (int off = 1; off < 1024; off <<= 1) {
        int v = (t >= off) ? sums[t - off] : 0;
        __syncthreads();
        sums[t] += v;
        __syncthreads();
    }
    int run = (t == 0) ? 0 : sums[t - 1];
    for (int i = beg; i < end; ++i) {
        row_start[i] = run;
        run += counts[i];
    }
    if (t == 1023) row_start[n] = sums[1023];
}

__global__ __launch_bounds__(256) void scatter_kernel(const int* __restrict__ src,
                                                      const int* __restrict__ dst,
                                                      const int* __restrict__ row_start,
                                                      int* __restrict__ cursor,
                                                      int* __restrict__ edge_src, int E) {
    int e = blockIdx.x * blockDim.x + threadIdx.x;
    if (e < E) {
        int d = dst[e];
        int pos = row_start[d] + atomicAdd(&cursor[d], 1);
        edge_src[pos] = src[e];
    }
}

// ---------------- bf16 helpers ----------------

__device__ __forceinline__ void split1(float v, ushort_t& h, ushort_t& l) {
    unsigned u = __float_as_uint(v);
    unsigned rh = u + 0x7FFFu + ((u >> 16) & 1u);
    h = (ushort_t)(rh >> 16);
    float hf = __uint_as_float((unsigned)h << 16);
    float rem = v - hf;
    unsigned u2 = __float_as_uint(rem);
    unsigned rl = u2 + 0x7FFFu + ((u2 >> 16) & 1u);
    l = (ushort_t)(rl >> 16);
}

__device__ __forceinline__ ushort_t f2bf(float v) {
    unsigned u = __float_as_uint(v);
    return (ushort_t)((u + 0x7FFFu + ((u >> 16) & 1u)) >> 16);
}

__device__ __forceinline__ float bf2f(ushort_t u) {
    return __uint_as_float((unsigned)u << 16);
}

// ---------------- prep: weight transposes/splits + padded a1 + histogram ----------------
// w1t [HC1P][FIN]: padded out-col n -> orig col (n>>5)*30 + (n&31) if (n&31)<30
// w2t [HC2][HC1P]: padded k  -> orig row (k>>5)*30 + (k&31)
// wlt [NCLS][HC2]: plain transpose
// a1sP/a1dP [HC1P]: padded attention vectors (zeros on pads)
// hist: counts[dst[e]]++

__global__ __launch_bounds__(256) void prep_kernel(
    const float* __restrict__ W1, const float* __restrict__ W2,
    const float* __restrict__ Wl,
    const float* __restrict__ a1s, const float* __restrict__ a1d,
    const int* __restrict__ dst,
    ushort_t* __restrict__ t1h, ushort_t* __restrict__ t1l,
    ushort_t* __restrict__ t2h, ushort_t* __restrict__ t2l,
    ushort_t* __restrict__ t3h, ushort_t* __restrict__ t3l,
    float* __restrict__ a1sP, float* __restrict__ a1dP,
    int* __restrict__ counts) {
    int idx = blockIdx.x * 256 + threadIdx.x;
    if (idx < TS1) {
        int n = idx >> 9, k = idx & 511;
        int cc = n & 31;
        float v = (cc < 30) ? W1[(size_t)k * HC1 + ((n >> 5) * 30 + cc)] : 0.f;
        ushort_t h, l;
        split1(v, h, l);
        t1h[idx] = h;
        t1l[idx] = l;
    } else if (idx < TS1 + TS2) {
        int lo = idx - TS1;
        int n = lo >> 8, k = lo & 255;
        int cc = k & 31;
        float v = (cc < 30) ? W2[(size_t)((k >> 5) * 30 + cc) * HC2 + n] : 0.f;
        ushort_t h, l;
        split1(v, h, l);
        t2h[lo] = h;
        t2l[lo] = l;
    } else if (idx < TS1 + TS2 + TS3) {
        int lo = idx - TS1 - TS2;
        int n = lo >> 9, k = lo & 511;
        float v = Wl[(size_t)k * NCLS + n];
        ushort_t h, l;
        split1(v, h, l);
        t3h[lo] = h;
        t3l[lo] = l;
    } else if (idx < TS1 + TS2 + TS3 + 2 * HC1P) {
        int j = idx - (TS1 + TS2 + TS3);
        int c = j & (HC1P - 1);
        int cc = c & 31;
        float vs = (cc < 30) ? a1s[(c >> 5) * 30 + cc] : 0.f;
        float vd = (cc < 30) ? a1d[(c >> 5) * 30 + cc] : 0.f;
        if (j < HC1P) a1sP[c] = vs;
        else          a1dP[c] = vd;
    } else {
        int e = idx - (TS1 + TS2 + TS3 + 2 * HC1P);
        if (e < EE) atomicAdd(&counts[dst[e]], 1);
    }
}

// ---------------- split-bf16 MFMA GEMM ----------------
// C[M x NP] = A[M x K] @ B; B pre-transposed/split [NP][K] bf16 hi/lo.
// Tile (32*TM) x (32*TN), BK=32, 256 threads = 4 waves (2x2).
// ASPLIT: A given as pre-split bf16 hi/lo tables [M][K].
// TPH>0: fused attention scores; head spans 16*TPH cols (requires TN=4).

template <int TM, int TN, bool ASPLIT, bool BIAS, bool WF32, bool WBF, int TPH>
__global__ __launch_bounds__(256) void gemm_mfma(const float* __restrict__ A,
                                                 const ushort_t* __restrict__ Ath,
                                                 const ushort_t* __restrict__ Atl,
                                                 const ushort_t* __restrict__ Bth,
                                                 const ushort_t* __restrict__ Btl,
                                                 const float* __restrict__ bias,
                                                 float* __restrict__ C,
                                                 ushort_t* __restrict__ Cbf,
                                                 const float* __restrict__ att_s,
                                                 const float* __restrict__ att_d,
                                                 float* __restrict__ asrc,
                                                 float* __restrict__ adst,
                                                 int M, int K, int CS) {
    constexpr int ROWS = 32 * TM;
    constexpr int BN = 32 * TN;
    constexpr int SK = 40;  // LDS stride (shorts): <=2-way conflicts (free)
    __shared__ ushort_t Ah[ROWS * SK], Al[ROWS * SK];
    __shared__ ushort_t Bh[BN * SK], Bl[BN * SK];
    const int t    = threadIdx.x;
    const int lane = t & 63;
    const int wave = t >> 6;
    const int quad = lane >> 4;
    const int l16  = lane & 15;
    const int wm   = wave >> 1;
    const int wn   = wave & 1;
    const int bm   = blockIdx.x * ROWS;
    const int bn   = blockIdx.y * BN;

    v4f acc[TM][TN];
    #pragma unroll
    for (int i = 0; i < TM; ++i)
        #pragma unroll
        for (int j = 0; j < TN; ++j) acc[i][j] = 0.f;

    for (int k0 = 0; k0 < K; k0 += 32) {
        if (k0) __syncthreads();
        // stage A
        #pragma unroll
        for (int idx = t; idx < ROWS * 4; idx += 256) {
            int row = idx >> 2;
            int kcb = (idx & 3) * 8;
            int gm = bm + row;
            u16x8 hv, lv;
            if (ASPLIT) {
                if (gm < M) {
                    size_t go = (size_t)gm * K + k0 + kcb;
                    hv = *(const u16x8*)(Ath + go);
                    lv = *(const u16x8*)(Atl + go);
                } else {
                    #pragma unroll
                    for (int i = 0; i < 8; ++i) { hv[i] = 0; lv[i] = 0; }
                }
            } else {
                float va[8];
                if (gm < M) {
                    const float* Ap = A + (size_t)gm * K + k0 + kcb;
                    float4 p = *(const float4*)Ap;
                    float4 q = *(const float4*)(Ap + 4);
                    va[0] = p.x; va[1] = p.y; va[2] = p.z; va[3] = p.w;
                    va[4] = q.x; va[5] = q.y; va[6] = q.z; va[7] = q.w;
                } else {
                    #pragma unroll
                    for (int i = 0; i < 8; ++i) va[i] = 0.f;
                }
                #pragma unroll
                for (int i = 0; i < 8; ++i) {
                    ushort_t h, l;
                    split1(va[i], h, l);
                    hv[i] = h;
                    lv[i] = l;
                }
            }
            *(u16x8*)&Ah[row * SK + kcb] = hv;
            *(u16x8*)&Al[row * SK + kcb] = lv;
        }
        // stage B
        #pragma unroll
        for (int idx = t; idx < BN * 4; idx += 256) {
            int row = idx >> 2;
            int kcb = (idx & 3) * 8;
            size_t go = (size_t)(bn + row) * K + k0 + kcb;
            *(u16x8*)&Bh[row * SK + kcb] = *(const u16x8*)(Bth + go);
            *(u16x8*)&Bl[row * SK + kcb] = *(const u16x8*)(Btl + go);
        }
        __syncthreads();

        v8s ah[TM], al2[TM], bh2[TN], bl2[TN];
        #pragma unroll
        for (int tt = 0; tt < TM; ++tt) {
            int ma = (wm * 16 * TM + tt * 16 + l16) * SK + quad * 8;
            ah[tt]  = *(const v8s*)&Ah[ma];
            al2[tt] = *(const v8s*)&Al[ma];
        }
        #pragma unroll
        for (int tn = 0; tn < TN; ++tn) {
            int nb = (wn * 16 * TN + tn * 16 + l16) * SK + quad * 8;
            bh2[tn] = *(const v8s*)&Bh[nb];
            bl2[tn] = *(const v8s*)&Bl[nb];
        }
        #pragma unroll
        for (int tm = 0; tm < TM; ++tm)
            #pragma unroll
            for (int tn = 0; tn < TN; ++tn) {
                acc[tm][tn] = __builtin_amdgcn_mfma_f32_16x16x32_bf16(
                    ah[tm], bh2[tn], acc[tm][tn], 0, 0, 0);
                acc[tm][tn] = __builtin_amdgcn_mfma_f32_16x16x32_bf16(
                    ah[tm], bl2[tn], acc[tm][tn], 0, 0, 0);
                acc[tm][tn] = __builtin_amdgcn_mfma_f32_16x16x32_bf16(
                    al2[tm], bh2[tn], acc[tm][tn], 0, 0, 0);
            }
    }

    // epilogue: C/D layout col=lane&15, row=quad*4+reg
    #pragma unroll
    for (int tm = 0; tm < TM; ++tm) {
        #pragma unroll
        for (int tn = 0; tn < TN; ++tn) {
            int row0 = bm + wm * 16 * TM + tm * 16 + quad * 4;
            int col  = bn + wn * 16 * TN + tn * 16 + l16;
            float badd = BIAS ? bias[col] : 0.f;
            #pragma unroll
            for (int reg = 0; reg < 4; ++reg) {
                int row = row0 + reg;
                if (row < M) {
                    float v = acc[tm][tn][reg] + badd;
                    if (WF32) C[(size_t)row * CS + col] = v;
                    if (WBF) Cbf[(size_t)row * CS + col] = f2bf(v);
                }
            }
        }
    }

    // fused attention scores: head spans 16*TPH contiguous cols
    if constexpr (TPH > 0) {
        constexpr int GR = TN / TPH;
        float aS[TN], aD[TN];
        #pragma unroll
        for (int tn = 0; tn < TN; ++tn) {
            int col = bn + wn * 16 * TN + tn * 16 + l16;
            aS[tn] = att_s[col];
            aD[tn] = att_d[col];
        }
        #pragma unroll
        for (int tm = 0; tm < TM; ++tm) {
            #pragma unroll
            for (int reg = 0; reg < 4; ++reg) {
                #pragma unroll
                for (int g = 0; g < GR; ++g) {
                    float ss = 0.f, sd = 0.f;
                    #pragma unroll
                    for (int ti = 0; ti < TPH; ++ti) {
                        int tn = g * TPH + ti;
                        ss += acc[tm][tn][reg] * aS[tn];
                        sd += acc[tm][tn][reg] * aD[tn];
                    }
                    #pragma unroll
                    for (int off = 1; off < 16; off <<= 1) {
                        ss += __shfl_xor(ss, off);
                        sd += __shfl_xor(sd, off);
                    }
                    if (l16 == 0) {
                        int row = bm + wm * 16 * TM + tm * 16 + quad * 4 + reg;
                        if (row < M) {
                            int head = (bn + wn * 16 * TN + g * 16 * TPH) / (16 * TPH);
                            asrc[row * NH + head] = ss;
                            adst[row * NH + head] = sd;
                        }
                    }
                }
            }
        }
    }
}

// ---------------- unified fused softmax aggregation ----------------
// 1 wave / dst node, CPL channels/lane (row = 64*CPL chans, head = lane>>3).
// Online softmax, depth-1 prefetch over 4-edge groups.
// OSPLIT: write split hi/lo bf16 (layer 1 -> feeds ASPLIT GEMM).
// PADB: bias indexed through the padded->orig channel map.

template <int CPL, bool ELU, bool OSPLIT, bool PADB>
__global__ __launch_bounds__(256) void agg_u(const ushort_t* __restrict__ hb,
                                             const float* __restrict__ asrc,
                                             const float* __restrict__ adst,
                                             const int* __restrict__ row_start,
                                             const int* __restrict__ edge_src,
                                             const float* __restrict__ bias,
                                             float* __restrict__ outf,
                                             ushort_t* __restrict__ outh,
                                             ushort_t* __restrict__ outl,
                                             int n) {
    constexpr int RSB = CPL * 64;
    using VT = typename std::conditional<CPL == 8, u16x8, u16x4v>::type;
    const int d    = (blockIdx.x * blockDim.x + threadIdx.x) >> 6;
    const int lane = threadIdx.x & 63;
    if (d >= n) return;
    const int head = lane >> 3;

    const float adh = (lane < NH) ? adst[d * NH + lane] : 0.f;

    float m, s;
    float ac[CPL];
    {
        float a = (lane < NH) ? asrc[d * NH + lane] + adh : 0.f;
        a = fmaxf(a, 0.2f * a);
        m = a;
        s = 1.f;
        VT u = *(const VT*)(hb + (size_t)d * RSB + CPL * lane);
        #pragma unroll
        for (int i = 0; i < CPL; ++i) ac[i] = bf2f(u[i]);
    }

    const int beg = row_start[d];
    const int end = row_start[d + 1];

    auto LD = [&](int eb, VT* rr, float* ss) {
        int i0 = edge_src[eb], i1 = edge_src[eb + 1];
        int i2 = edge_src[eb + 2], i3 = edge_src[eb + 3];
        rr[0] = *(const VT*)(hb + (size_t)i0 * RSB + CPL * lane);
        rr[1] = *(const VT*)(hb + (size_t)i1 * RSB + CPL * lane);
        rr[2] = *(const VT*)(hb + (size_t)i2 * RSB + CPL * lane);
        rr[3] = *(const VT*)(hb + (size_t)i3 * RSB + CPL * lane);
        if (lane < NH) {
            ss[0] = asrc[i0 * NH + lane];
            ss[1] = asrc[i1 * NH + lane];
            ss[2] = asrc[i2 * NH + lane];
            ss[3] = asrc[i3 * NH + lane];
        } else {
            ss[0] = ss[1] = ss[2] = ss[3] = 0.f;
        }
    };
    auto PR = [&](const VT* rr, const float* ss) {
        float a0 = ss[0] + adh, a1 = ss[1] + adh, a2 = ss[2] + adh, a3 = ss[3] + adh;
        a0 = fmaxf(a0, 0.2f * a0);
        a1 = fmaxf(a1, 0.2f * a1);
        a2 = fmaxf(a2, 0.2f * a2);
        a3 = fmaxf(a3, 0.2f * a3);
        float mn = fmaxf(m, fmaxf(fmaxf(a0, a1), fmaxf(a2, a3)));
        float al = __expf(m - mn);
        float w0 = __expf(a0 - mn);
        float w1 = __expf(a1 - mn);
        float w2 = __expf(a2 - mn);
        float w3 = __expf(a3 - mn);
        s = s * al + (w0 + w1) + (w2 + w3);
        m = mn;
        float alc = __shfl(al, head);
        float c0 = __shfl(w0, head);
        float c1 = __shfl(w1, head);
        float c2 = __shfl(w2, head);
        float c3 = __shfl(w3, head);
        #pragma unroll
        for (int i = 0; i < CPL; ++i)
            ac[i] = ac[i] * alc + c0 * bf2f(rr[0][i]) + c1 * bf2f(rr[1][i]) +
                    c2 * bf2f(rr[2][i]) + c3 * bf2f(rr[3][i]);
    };

    int e = beg;
    const int ng = (end - beg) >> 2;
    if (ng > 0) {
        VT cr[4];
        float cs[4];
        LD(e, cr, cs);
        for (int g = 1; g < ng; ++g) {
            VT nr[4];
            float ns[4];
            LD(e + 4 * g, nr, ns);
            PR(cr, cs);
            #pragma unroll
            for (int j = 0; j < 4; ++j) { cr[j] = nr[j]; cs[j] = ns[j]; }
        }
        PR(cr, cs);
        e += 4 * ng;
    }
    for (; e < end; ++e) {
        int i0 = edge_src[e];
        VT r0 = *(const VT*)(hb + (size_t)i0 * RSB + CPL * lane);
        float a0 = (lane < NH) ? asrc[i0 * NH + lane] + adh : 0.f;
        a0 = fmaxf(a0, 0.2f * a0);
        float mn = fmaxf(m, a0);
        float al = __expf(m - mn);
        float w0 = __expf(a0 - mn);
        s = s * al + w0;
        m = mn;
        float alc = __shfl(al, head);
        float c0w = __shfl(w0, head);
        #pragma unroll
        for (int i = 0; i < CPL; ++i) ac[i] = ac[i] * alc + c0w * bf2f(r0[i]);
    }

    float inv = 1.f / s;
    float ivc = __shfl(inv, head);
    float o[CPL];
    if constexpr (PADB) {
        const int c = CPL * lane;
        const int cc = c & 31;
        const int bbase = (c >> 5) * 30 + cc;
        #pragma unroll
        for (int i = 0; i < CPL; ++i) {
            float b = (cc + i < 30) ? bias[bbase + i] : 0.f;
            o[i] = ac[i] * ivc + b;   // pad channels: 0*ivc + 0 = 0
        }
    } else {
        #pragma unroll
        for (int i = 0; i < CPL; ++i) o[i] = ac[i] * ivc + bias[CPL * lane + i];
    }
    if (ELU) {
        #pragma unroll
        for (int i = 0; i < CPL; ++i) o[i] = (o[i] > 0.f) ? o[i] : __expf(o[i]) - 1.f;
    }
    if constexpr (OSPLIT) {
        VT hh, ll;
        #pragma unroll
        for (int i = 0; i < CPL; ++i) {
            ushort_t h2, l2;
            split1(o[i], h2, l2);
            hh[i] = h2;
            ll[i] = l2;
        }
        *(VT*)(outh + (size_t)d * RSB + CPL * lane) = hh;
        *(VT*)(outl + (size_t)d * RSB + CPL * lane) = ll;
    } else {
        float4* orow = (float4*)(outf + (size_t)d * RSB);
        #pragma unroll
        for (int q = 0; q < CPL / 4; ++q) {
            float4 v;
            v.x = o[4 * q + 0];
            v.y = o[4 * q + 1];
            v.z = o[4 * q + 2];
            v.w = o[4 * q + 3];
            orow[(CPL / 4) * lane + q] = v;
        }
    }
}

// ---------------- launch ----------------

extern "C" void kernel_launch(void* const* d_in, const int* in_sizes, int n_in,
                              void* d_out, int out_size, void* d_ws, size_t ws_size,
                              hipStream_t stream) {
    const float* x      = (const float*)d_in[0];
    const int*   eidx   = (const int*)d_in[1];   // [2, E]
    const float* W1     = (const float*)d_in[2];
    const float* a1_src = (const float*)d_in[3];
    const float* a1_dst = (const float*)d_in[4];
    const float* b1     = (const float*)d_in[5];
    const float* W2     = (const float*)d_in[6];
    const float* a2_src = (const float*)d_in[7];
    const float* a2_dst = (const float*)d_in[8];
    const float* b2     = (const float*)d_in[9];
    const float* Wlin   = (const float*)d_in[10];
    const float* blin   = (const float*)d_in[11];

    const int* src = eidx;        // row 0
    const int* dst = eidx + EE;   // row 1

    float* out0  = (float*)d_out;                      // [N, NCLS]
    float* h_out = (float*)d_out + (size_t)NN * NCLS;  // [N, HC2] (output 1)

    // workspace layout: floats, then ushorts, then ints
    float* f = (float*)d_ws;
    float* asrc1 = f;
    float* adst1 = asrc1 + NN * NH;
    float* asrc2 = adst1 + NN * NH;
    float* adst2 = asrc2 + NN * NH;
    float* a1sP  = adst2 + NN * NH;          // [HC1P]
    float* a1dP  = a1sP + HC1P;              // [HC1P]
    ushort_t* w1t_h = (ushort_t*)(a1dP + HC1P);
    ushort_t* w1t_l = w1t_h + TS1;
    ushort_t* w2t_h = w1t_l + TS1;
    ushort_t* w2t_l = w2t_h + TS2;
    ushort_t* wlt_h = w2t_l + TS2;
    ushort_t* wlt_l = wlt_h + TS3;
    ushort_t* h1p_bf = wlt_l + TS3;                  // [NN][HC1P] bf16 (pre-agg)
    ushort_t* h1h    = h1p_bf + (size_t)NN * HC1P;   // [NN][HC1P] hi (post-agg)
    ushort_t* h1l    = h1h + (size_t)NN * HC1P;      // [NN][HC1P] lo
    ushort_t* h2p_bf = h1l + (size_t)NN * HC1P;      // [NN][HC2] bf16 (pre-agg)
    int* counts    = (int*)(h2p_bf + (size_t)NN * HC2);
    int* cursor    = counts + NN;
    int* row_start = cursor + NN;            // N+1
    int* edge_src  = row_start + NN + 1;     // E

    hipMemsetAsync(counts, 0, 2 * NN * sizeof(int), stream);

    // prep: all transposes/splits + padded a1 vectors + degree histogram
    {
        const int total = TS1 + TS2 + TS3 + 2 * HC1P + EE;
        prep_kernel<<<(total + 255) / 256, 256, 0, stream>>>(
            W1, W2, Wlin, a1_src, a1_dst, dst, w1t_h, w1t_l, w2t_h, w2t_l,
            wlt_h, wlt_l, a1sP, a1dP, counts);
    }
    scan_kernel<<<1, 1024, 0, stream>>>(counts, row_start, NN);
    scatter_kernel<<<(EE + 255) / 256, 256, 0, stream>>>(src, dst, row_start, cursor,
                                                         edge_src, EE);

    const int MB = (NN + 63) / 64;  // 157

    // Layer 1: h1p_bf[NN][256] = x @ W1 (bf16 only) + fused att1 (head = 32 cols)
    {
        dim3 grid(MB, HC1P / 128);
        gemm_mfma<2, 4, false, false, false, true, 2><<<grid, 256, 0, stream>>>(
            x, nullptr, nullptr, w1t_h, w1t_l, nullptr, nullptr, h1p_bf,
            a1sP, a1dP, asrc1, adst1, NN, FIN, HC1P);
    }
    // agg1: 4 ch/lane, ELU, writes split hi/lo bf16 h1
    agg_u<4, true, true, true><<<(NN + 3) / 4, 256, 0, stream>>>(
        h1p_bf, asrc1, adst1, row_start, edge_src, b1, nullptr, h1h, h1l, NN);

    // Layer 2: h2p_bf = h1 @ W2 (A pre-split) + fused att2 (head = 64 cols)
    {
        dim3 grid(MB, HC2 / 128);
        gemm_mfma<2, 4, true, false, false, true, 4><<<grid, 256, 0, stream>>>(
            nullptr, h1h, h1l, w2t_h, w2t_l, nullptr, nullptr, h2p_bf,
            a2_src, a2_dst, asrc2, adst2, NN, HC1P, HC2);
    }
    // agg2: 8 ch/lane, no ELU, writes fp32 h_out (output 1)
    agg_u<8, false, false, false><<<(NN + 3) / 4, 256, 0, stream>>>(
        h2p_bf, asrc2, adst2, row_start, edge_src, b2, h_out, nullptr, nullptr, NN);

    // Head: out0 = h_out @ Wlin + blin
    {
        dim3 grid((NN + 31) / 32, NCLS / 64);
        gemm_mfma<1, 2, false, true, true, false, 0><<<grid, 256, 0, stream>>>(
            h_out, nullptr, nullptr, wlt_h, wlt_l, blin, out0, nullptr,
            nullptr, nullptr, nullptr, nullptr, NN, HC2, NCLS);
    }
}